// Round 4
// baseline (383.277 us; speedup 1.0000x reference)
//
#include <hip/hip_runtime.h>

// Problem constants (reference: B=4096, T=256, D=64)
#define DD 64
#define TT 256
#define BB 4096
#define KTERMS 16   // Taylor degree: ||A*t|| <~ 0.85 -> tail ~1e-12, below f32 eps

// ---------------------------------------------------------------------------
// Kernel 1: E[t] = expm((W*mask) * t)  via degree-16 Taylor in Horner form.
// One block per t. 512 threads; each thread owns a 2x4 tile of the 64x64
// matmul per Horner step.
// ---------------------------------------------------------------------------
__global__ __launch_bounds__(512, 1) void expm_taylor(
    const float* __restrict__ W, const int* __restrict__ mask,
    const float* __restrict__ t_span, float* __restrict__ Eg)
{
    __shared__ float P[DD][DD + 1];   // A*t, padded
    __shared__ float M[DD][DD];       // Horner state

    const int t   = blockIdx.x;
    const float tv = t_span[t];
    const int tid = threadIdx.x;

    // P = (W .* mask) * t   (4096 elements, 8 per thread, coalesced)
    // mask is a bool array uploaded as int32 (harness: integer -> const int*)
    #pragma unroll
    for (int i = 0; i < 8; ++i) {
        const int idx = tid + i * 512;
        const int r = idx >> 6, c = idx & 63;
        const float w = W[idx] * tv;
        P[r][c] = (mask[idx] != 0) ? w : 0.0f;
    }
    __syncthreads();

    // M = I + P/K   (innermost Horner step, saves one matmul)
    #pragma unroll
    for (int i = 0; i < 8; ++i) {
        const int idx = tid + i * 512;
        const int r = idx >> 6, c = idx & 63;
        M[r][c] = P[r][c] * (1.0f / (float)KTERMS) + ((r == c) ? 1.0f : 0.0f);
    }
    __syncthreads();

    const int ct = tid & 15;    // column tile: cols ct*4 .. ct*4+3
    const int rt = tid >> 4;    // row tile:    rows rt*2 .. rt*2+1
    const int c0 = ct * 4;
    const int r0 = rt * 2;

    for (int j = KTERMS - 1; j >= 1; --j) {
        const float inv = 1.0f / (float)j;
        float a0[4] = {0.f, 0.f, 0.f, 0.f};
        float a1[4] = {0.f, 0.f, 0.f, 0.f};
        #pragma unroll
        for (int k = 0; k < DD; ++k) {
            const float p0 = P[r0 + 0][k];
            const float p1 = P[r0 + 1][k];
            const float4 b = *reinterpret_cast<const float4*>(&M[k][c0]);
            a0[0] += p0 * b.x; a0[1] += p0 * b.y; a0[2] += p0 * b.z; a0[3] += p0 * b.w;
            a1[0] += p1 * b.x; a1[1] += p1 * b.y; a1[2] += p1 * b.z; a1[3] += p1 * b.w;
        }
        __syncthreads();   // all reads of M done before overwrite
        M[r0 + 0][c0 + 0] = a0[0] * inv + ((r0 + 0 == c0 + 0) ? 1.f : 0.f);
        M[r0 + 0][c0 + 1] = a0[1] * inv + ((r0 + 0 == c0 + 1) ? 1.f : 0.f);
        M[r0 + 0][c0 + 2] = a0[2] * inv + ((r0 + 0 == c0 + 2) ? 1.f : 0.f);
        M[r0 + 0][c0 + 3] = a0[3] * inv + ((r0 + 0 == c0 + 3) ? 1.f : 0.f);
        M[r0 + 1][c0 + 0] = a1[0] * inv + ((r0 + 1 == c0 + 0) ? 1.f : 0.f);
        M[r0 + 1][c0 + 1] = a1[1] * inv + ((r0 + 1 == c0 + 1) ? 1.f : 0.f);
        M[r0 + 1][c0 + 2] = a1[2] * inv + ((r0 + 1 == c0 + 2) ? 1.f : 0.f);
        M[r0 + 1][c0 + 3] = a1[3] * inv + ((r0 + 1 == c0 + 3) ? 1.f : 0.f);
        __syncthreads();
    }

    // Eg[t][k][d] = M[k][d]  (row-major, coalesced dword stores)
    #pragma unroll
    for (int i = 0; i < 8; ++i) {
        const int idx = tid + i * 512;
        const int r = idx >> 6, c = idx & 63;
        Eg[(size_t)t * (DD * DD) + idx] = M[r][c];
    }
}

// ---------------------------------------------------------------------------
// Kernel 2: out[b,t,k] = sum_d Y[b,d] * E[t][k,d] + xs[k],  Y = X0 - x_star.
// Block = (one t) x (64 rows of b). E transposed into LDS (Es[d][k]) so the
// inner d-loop reads Es rows as float4. 4x4 register tile per thread.
// LDS stride 68 keeps float4 ops 16B-aligned (68*4=272=16*17) and bank
// aliasing <= 2-way.
// ---------------------------------------------------------------------------
__global__ __launch_bounds__(256, 1) void propagate(
    const float* __restrict__ X0, const float* __restrict__ xs,
    const float* __restrict__ Eg, float* __restrict__ out)
{
    __shared__ float Ys[64][68];
    __shared__ float Es[64][68];   // Es[d][k] = E[t][k][d]

    const int t   = blockIdx.x;
    const int b0  = blockIdx.y << 6;
    const int tid = threadIdx.x;

    // Load Y tile = X0 - x_star (16 KB, float4-coalesced)
    {
        const int f   = tid & 15;      // float4 chunk within a row
        const int row = tid >> 4;      // 16 rows per pass, 4 passes
        const float4 xv = reinterpret_cast<const float4*>(xs)[f];
        #pragma unroll
        for (int p = 0; p < 4; ++p) {
            const int rr = row + p * 16;
            float4 v = reinterpret_cast<const float4*>(X0 + (size_t)(b0 + rr) * DD)[f];
            v.x -= xv.x; v.y -= xv.y; v.z -= xv.z; v.w -= xv.w;
            *reinterpret_cast<float4*>(&Ys[rr][f * 4]) = v;
        }
    }
    // Load E[t] and transpose into Es[d][k]
    {
        const float4* Esrc = reinterpret_cast<const float4*>(Eg + (size_t)t * (DD * DD));
        #pragma unroll
        for (int p = 0; p < 4; ++p) {
            const int ch = tid + p * 256;       // 1024 float4 chunks total
            const int k  = ch >> 4;             // source row (output index k)
            const int d0 = (ch & 15) * 4;       // source cols (input index d)
            const float4 e = Esrc[ch];
            Es[d0 + 0][k] = e.x;
            Es[d0 + 1][k] = e.y;
            Es[d0 + 2][k] = e.z;
            Es[d0 + 3][k] = e.w;
        }
    }
    __syncthreads();

    const int ct = tid & 15;    // k-tile
    const int bt = tid >> 4;    // b-tile
    const int c0 = ct * 4;
    const int bb = bt * 4;

    float acc[4][4] = {{0.f}};
    #pragma unroll
    for (int d = 0; d < DD; ++d) {
        const float4 e = *reinterpret_cast<const float4*>(&Es[d][c0]);
        #pragma unroll
        for (int i = 0; i < 4; ++i) {
            const float y = Ys[bb + i][d];
            acc[i][0] += y * e.x;
            acc[i][1] += y * e.y;
            acc[i][2] += y * e.z;
            acc[i][3] += y * e.w;
        }
    }

    const float4 xv = reinterpret_cast<const float4*>(xs)[ct];
    #pragma unroll
    for (int i = 0; i < 4; ++i) {
        float4 o;
        o.x = acc[i][0] + xv.x;
        o.y = acc[i][1] + xv.y;
        o.z = acc[i][2] + xv.z;
        o.w = acc[i][3] + xv.w;
        float* dst = out + ((size_t)(b0 + bb + i) * TT + t) * DD + c0;
        *reinterpret_cast<float4*>(dst) = o;
    }
}

// ---------------------------------------------------------------------------
extern "C" void kernel_launch(void* const* d_in, const int* in_sizes, int n_in,
                              void* d_out, int out_size, void* d_ws, size_t ws_size,
                              hipStream_t stream)
{
    // setup_inputs order: X0[B,D] f32, t_span[T] f32, W[D,D] f32,
    //                     x_star[D] f32, mask[D,D] bool (uploaded as int32)
    const float* X0     = (const float*)d_in[0];
    const float* t_span = (const float*)d_in[1];
    const float* W      = (const float*)d_in[2];
    const float* xs     = (const float*)d_in[3];
    const int*   mask   = (const int*)d_in[4];
    float*       out    = (float*)d_out;
    float*       Eg     = (float*)d_ws;   // T*D*D f32 = 4 MB scratch

    expm_taylor<<<TT, 512, 0, stream>>>(W, mask, t_span, Eg);
    propagate<<<dim3(TT, BB / 64), 256, 0, stream>>>(X0, xs, Eg, out);
}

// Round 5
// 333.055 us; speedup vs baseline: 1.1508x; 1.1508x over previous
//
#include <hip/hip_runtime.h>

// Problem constants (reference: B=4096, T=256, D=64)
#define DD 64
#define TT 256
#define BB 4096
#define KTERMS 16   // Taylor degree: ||A*t|| <~ 0.85 -> tail ~1e-12, below f32 eps

typedef __attribute__((ext_vector_type(8))) short bf16x8;   // 8 bf16 (4 VGPRs)
typedef __attribute__((ext_vector_type(4))) float f32x4;    // MFMA acc

__device__ inline unsigned short f32_to_bf16_rne(float x) {
    unsigned int u = __float_as_uint(x);
    unsigned int r = (u + 0x7FFFu + ((u >> 16) & 1u)) >> 16;
    return (unsigned short)r;
}
__device__ inline float bf16_to_f32(unsigned short h) {
    return __uint_as_float(((unsigned int)h) << 16);
}

// ---------------------------------------------------------------------------
// Kernel 1: E[t] = expm((W*mask) * t) via degree-16 Taylor, Horner form.
// UNCHANGED from the round-4 passing version (one risky change per round).
// ---------------------------------------------------------------------------
__global__ __launch_bounds__(512, 1) void expm_taylor(
    const float* __restrict__ W, const int* __restrict__ mask,
    const float* __restrict__ t_span, float* __restrict__ Eg)
{
    __shared__ float P[DD][DD + 1];   // A*t, padded
    __shared__ float M[DD][DD];       // Horner state

    const int t   = blockIdx.x;
    const float tv = t_span[t];
    const int tid = threadIdx.x;

    #pragma unroll
    for (int i = 0; i < 8; ++i) {
        const int idx = tid + i * 512;
        const int r = idx >> 6, c = idx & 63;
        const float w = W[idx] * tv;
        P[r][c] = (mask[idx] != 0) ? w : 0.0f;
    }
    __syncthreads();

    #pragma unroll
    for (int i = 0; i < 8; ++i) {
        const int idx = tid + i * 512;
        const int r = idx >> 6, c = idx & 63;
        M[r][c] = P[r][c] * (1.0f / (float)KTERMS) + ((r == c) ? 1.0f : 0.0f);
    }
    __syncthreads();

    const int ct = tid & 15;
    const int rt = tid >> 4;
    const int c0 = ct * 4;
    const int r0 = rt * 2;

    for (int j = KTERMS - 1; j >= 1; --j) {
        const float inv = 1.0f / (float)j;
        float a0[4] = {0.f, 0.f, 0.f, 0.f};
        float a1[4] = {0.f, 0.f, 0.f, 0.f};
        #pragma unroll
        for (int k = 0; k < DD; ++k) {
            const float p0 = P[r0 + 0][k];
            const float p1 = P[r0 + 1][k];
            const float4 b = *reinterpret_cast<const float4*>(&M[k][c0]);
            a0[0] += p0 * b.x; a0[1] += p0 * b.y; a0[2] += p0 * b.z; a0[3] += p0 * b.w;
            a1[0] += p1 * b.x; a1[1] += p1 * b.y; a1[2] += p1 * b.z; a1[3] += p1 * b.w;
        }
        __syncthreads();
        M[r0 + 0][c0 + 0] = a0[0] * inv + ((r0 + 0 == c0 + 0) ? 1.f : 0.f);
        M[r0 + 0][c0 + 1] = a0[1] * inv + ((r0 + 0 == c0 + 1) ? 1.f : 0.f);
        M[r0 + 0][c0 + 2] = a0[2] * inv + ((r0 + 0 == c0 + 2) ? 1.f : 0.f);
        M[r0 + 0][c0 + 3] = a0[3] * inv + ((r0 + 0 == c0 + 3) ? 1.f : 0.f);
        M[r0 + 1][c0 + 0] = a1[0] * inv + ((r0 + 1 == c0 + 0) ? 1.f : 0.f);
        M[r0 + 1][c0 + 1] = a1[1] * inv + ((r0 + 1 == c0 + 1) ? 1.f : 0.f);
        M[r0 + 1][c0 + 2] = a1[2] * inv + ((r0 + 1 == c0 + 2) ? 1.f : 0.f);
        M[r0 + 1][c0 + 3] = a1[3] * inv + ((r0 + 1 == c0 + 3) ? 1.f : 0.f);
        __syncthreads();
    }

    #pragma unroll
    for (int i = 0; i < 8; ++i) {
        const int idx = tid + i * 512;
        const int r = idx >> 6, c = idx & 63;
        Eg[(size_t)t * (DD * DD) + idx] = M[r][c];
    }
}

// ---------------------------------------------------------------------------
// Kernel 2 (REWRITTEN): out[b,t,k] = sum_d Y[b,d]*E[t,k,d] + xs[k] via MFMA.
// bf16 3-product split: acc += Yh*Eh + Yl*Eh + Yh*El  (~f32 accuracy; the
// dropped Yl*El term is ~2^-16 relative).
// Block = 256 thr (4 waves), one t x 64 b-rows. Wave w owns b-rows w*16..+15,
// all 64 k-cols (4 n-tiles of 16). A = Y[64x64d], B = E[t] rows=k cols=d
// (both consumed along d => 16B ds_read_b128 frags, same k-slot convention
// for A and B so any HW k-permutation cancels).
// LDS tiles: bf16 [64][64] rows = 128B => XOR-swizzle byte^=((row&7)<<4)
// (T2) to break the 16-way bank conflict on stride-128B frag reads.
// ---------------------------------------------------------------------------
__global__ __launch_bounds__(256, 1) void propagate_mfma(
    const float* __restrict__ X0, const float* __restrict__ xs,
    const float* __restrict__ Eg, float* __restrict__ out)
{
    __shared__ __align__(16) unsigned short Yh[DD * DD];
    __shared__ __align__(16) unsigned short Yl[DD * DD];
    __shared__ __align__(16) unsigned short Ehs[DD * DD];
    __shared__ __align__(16) unsigned short Els[DD * DD];

    const int t   = blockIdx.x;
    const int b0  = blockIdx.y << 6;
    const int tid = threadIdx.x;

    // ---- stage Y = X0 - xs and E[t], each split hi/lo bf16, swizzled ----
    {
        const int f   = tid & 15;      // float4 chunk (cols f*4..f*4+3)
        const int row = tid >> 4;      // 16 rows per pass, 4 passes
        const float4 xv = reinterpret_cast<const float4*>(xs)[f];
        const float4* Esrc = reinterpret_cast<const float4*>(Eg + (size_t)t * (DD * DD));
        #pragma unroll
        for (int p = 0; p < 4; ++p) {
            const int r = row + p * 16;
            const int byte = r * 128 + f * 8;           // 4 bf16 = 8B
            const int swz  = byte ^ ((r & 7) << 4);     // T2 swizzle (bits 4-6)

            float4 v = reinterpret_cast<const float4*>(X0 + (size_t)(b0 + r) * DD)[f];
            v.x -= xv.x; v.y -= xv.y; v.z -= xv.z; v.w -= xv.w;
            ushort4 h, l;
            h.x = f32_to_bf16_rne(v.x); l.x = f32_to_bf16_rne(v.x - bf16_to_f32(h.x));
            h.y = f32_to_bf16_rne(v.y); l.y = f32_to_bf16_rne(v.y - bf16_to_f32(h.y));
            h.z = f32_to_bf16_rne(v.z); l.z = f32_to_bf16_rne(v.z - bf16_to_f32(h.z));
            h.w = f32_to_bf16_rne(v.w); l.w = f32_to_bf16_rne(v.w - bf16_to_f32(h.w));
            *reinterpret_cast<ushort4*>(reinterpret_cast<char*>(Yh) + swz) = h;
            *reinterpret_cast<ushort4*>(reinterpret_cast<char*>(Yl) + swz) = l;

            const float4 e = Esrc[r * 16 + f];
            ushort4 eh, el;
            eh.x = f32_to_bf16_rne(e.x); el.x = f32_to_bf16_rne(e.x - bf16_to_f32(eh.x));
            eh.y = f32_to_bf16_rne(e.y); el.y = f32_to_bf16_rne(e.y - bf16_to_f32(eh.y));
            eh.z = f32_to_bf16_rne(e.z); el.z = f32_to_bf16_rne(e.z - bf16_to_f32(eh.z));
            eh.w = f32_to_bf16_rne(e.w); el.w = f32_to_bf16_rne(e.w - bf16_to_f32(eh.w));
            *reinterpret_cast<ushort4*>(reinterpret_cast<char*>(Ehs) + swz) = eh;
            *reinterpret_cast<ushort4*>(reinterpret_cast<char*>(Els) + swz) = el;
        }
    }
    __syncthreads();

    const int lane = tid & 63;
    const int wave = tid >> 6;        // wave w -> b-rows w*16..w*16+15
    const int g    = lane >> 4;       // k-slot group
    const int r16  = lane & 15;       // non-K index for A and B frags

    // A frags: Y rows (m = wave*16 + r16), 16B along d; s in {0,1} = k0 {0,32}
    const int arow  = wave * 16 + r16;
    const int abyte = arow * 128 + g * 16;
    const int asw0  = abyte ^ ((arow & 7) << 4);
    const int asw1  = (abyte + 64) ^ ((arow & 7) << 4);
    const bf16x8 ah0 = *reinterpret_cast<const bf16x8*>(reinterpret_cast<const char*>(Yh) + asw0);
    const bf16x8 ah1 = *reinterpret_cast<const bf16x8*>(reinterpret_cast<const char*>(Yh) + asw1);
    const bf16x8 al0 = *reinterpret_cast<const bf16x8*>(reinterpret_cast<const char*>(Yl) + asw0);
    const bf16x8 al1 = *reinterpret_cast<const bf16x8*>(reinterpret_cast<const char*>(Yl) + asw1);

    f32x4 acc[4];
    #pragma unroll
    for (int nt = 0; nt < 4; ++nt) acc[nt] = (f32x4){0.f, 0.f, 0.f, 0.f};

    #pragma unroll
    for (int nt = 0; nt < 4; ++nt) {
        const int brow  = nt * 16 + r16;         // E row = output-k index
        const int bbyte = brow * 128 + g * 16;
        const int bsw0  = bbyte ^ ((brow & 7) << 4);
        const int bsw1  = (bbyte + 64) ^ ((brow & 7) << 4);
        const bf16x8 bh0 = *reinterpret_cast<const bf16x8*>(reinterpret_cast<const char*>(Ehs) + bsw0);
        const bf16x8 bh1 = *reinterpret_cast<const bf16x8*>(reinterpret_cast<const char*>(Ehs) + bsw1);
        const bf16x8 bl0 = *reinterpret_cast<const bf16x8*>(reinterpret_cast<const char*>(Els) + bsw0);
        const bf16x8 bl1 = *reinterpret_cast<const bf16x8*>(reinterpret_cast<const char*>(Els) + bsw1);

        acc[nt] = __builtin_amdgcn_mfma_f32_16x16x32_bf16(ah0, bh0, acc[nt], 0, 0, 0);
        acc[nt] = __builtin_amdgcn_mfma_f32_16x16x32_bf16(ah1, bh1, acc[nt], 0, 0, 0);
        acc[nt] = __builtin_amdgcn_mfma_f32_16x16x32_bf16(al0, bh0, acc[nt], 0, 0, 0);
        acc[nt] = __builtin_amdgcn_mfma_f32_16x16x32_bf16(al1, bh1, acc[nt], 0, 0, 0);
        acc[nt] = __builtin_amdgcn_mfma_f32_16x16x32_bf16(ah0, bl0, acc[nt], 0, 0, 0);
        acc[nt] = __builtin_amdgcn_mfma_f32_16x16x32_bf16(ah1, bl1, acc[nt], 0, 0, 0);
    }

    // C/D mapping (m89-verified): col = lane&15 (n = k-out), row = g*4+reg (m)
    #pragma unroll
    for (int nt = 0; nt < 4; ++nt) {
        const float xsv = xs[nt * 16 + r16];
        #pragma unroll
        for (int r = 0; r < 4; ++r) {
            const int m = wave * 16 + g * 4 + r;
            out[((size_t)(b0 + m) * TT + t) * DD + nt * 16 + r16] = acc[nt][r] + xsv;
        }
    }
}

// ---------------------------------------------------------------------------
extern "C" void kernel_launch(void* const* d_in, const int* in_sizes, int n_in,
                              void* d_out, int out_size, void* d_ws, size_t ws_size,
                              hipStream_t stream)
{
    // setup_inputs order: X0[B,D] f32, t_span[T] f32, W[D,D] f32,
    //                     x_star[D] f32, mask[D,D] bool (uploaded as int32)
    const float* X0     = (const float*)d_in[0];
    const float* t_span = (const float*)d_in[1];
    const float* W      = (const float*)d_in[2];
    const float* xs     = (const float*)d_in[3];
    const int*   mask   = (const int*)d_in[4];
    float*       out    = (float*)d_out;
    float*       Eg     = (float*)d_ws;   // T*D*D f32 = 4 MB scratch

    expm_taylor<<<TT, 512, 0, stream>>>(W, mask, t_span, Eg);
    propagate_mfma<<<dim3(TT, BB / 64), 256, 0, stream>>>(X0, xs, Eg, out);
}